// Round 14
// baseline (423.963 us; speedup 1.0000x reference)
//
#include <hip/hip_runtime.h>

#define NN 100000
#define NE 3200000
#define NA 60000
#define NB 40000
#define NHID 256
#define NOUT 64

#define RPB 64                    // rows per bucket
#define NBUCK 1563                // ceil(NN/64)
#define PBLK 256                  // partition blocks
#define CHUNK 12500               // NE / PBLK (exact)

#define WT_BLKS 704               // 180224 / 256
#define G1_BLKS 469               // ceil(NA/128), BN=256 single pass
#define G2_BLKS 313               // ceil(NB/128)
#define G3_BLKS 782               // ceil(NN/128)
#define G3A 391                   // gemm3 first half (rides with s2|p3)
#define G3B 391                   // gemm3 second half (rides with sort)

typedef unsigned short u16;
typedef unsigned int u32;
typedef __attribute__((ext_vector_type(8))) short short8;
typedef __attribute__((ext_vector_type(4))) float f32x4;

__device__ __forceinline__ float bf2f(u16 u) {
  return __uint_as_float(((u32)u) << 16);
}
__device__ __forceinline__ u16 f2bf(float f) {
  u32 u = __float_as_uint(f);
  u32 r = (u + 0x7fffu + ((u >> 16) & 1u)) >> 16;  // RNE
  return (u16)r;
}
__device__ __forceinline__ u16 f2h(float f) {   // f32 -> f16 bits (RNE)
  _Float16 h = (_Float16)f;
  u16 r;
  __builtin_memcpy(&r, &h, 2);
  return r;
}
__device__ __forceinline__ float h2f(u32 b15) { // 15-bit f16 (sign=0) -> f32
  u16 hb = (u16)b15;
  _Float16 h;
  __builtin_memcpy(&h, &hb, 2);
  return (float)h;
}

__device__ __forceinline__ void gload_lds16(const void* gsrc, void* ldst) {
  __builtin_amdgcn_global_load_lds(
      (const __attribute__((address_space(1))) void*)gsrc,
      (__attribute__((address_space(3))) void*)ldst, 16, 0, 0);
}

// ---------------------------------------------------------------------------
// 8-wave GEMM body: BM=128, BN=N=256, 512 threads (2x4 waves, 64x64 tiles).
// QUANT=0: relu+bf16 out. QUANT=1: BIASED-uint8 out (q+128), per-row-per-64col
// scale, lane-major pack (consumer subtracts 128*sum(vs)).
// ---------------------------------------------------------------------------
template <int QUANT>
__device__ __forceinline__ void gemm8_body(
    int bx, const u16* __restrict__ A, const u16* __restrict__ Bt,
    const float* __restrict__ bias, void* __restrict__ Cout,
    float* __restrict__ scales, int M, int K, u16* As, u16* Bs) {
  const int tid = threadIdx.x;
  const int w = tid >> 6;
  const int lane = tid & 63;
  const int bm = bx * 128;
  const int wr = w >> 2;   // 0..1
  const int wc = w & 3;    // 0..3

  f32x4 acc[4][4];
#pragma unroll
  for (int i = 0; i < 4; ++i)
#pragma unroll
    for (int j = 0; j < 4; ++j) acc[i][j] = (f32x4)0.f;

  for (int k0 = 0; k0 < K; k0 += 32) {
    {
      const int row = w * 16 + (lane >> 2);
      int rg = bm + row;
      if (rg > M - 1) rg = M - 1;
      const int c = (lane & 3) ^ ((row >> 1) & 3);
      gload_lds16(A + (size_t)rg * K + k0 + c * 8, &As[w * 512]);
    }
#pragma unroll
    for (int s = 0; s < 2; ++s) {
      const int inst = w * 2 + s;
      const int row = inst * 16 + (lane >> 2);
      const int c = (lane & 3) ^ ((row >> 1) & 3);
      gload_lds16(Bt + (size_t)row * K + k0 + c * 8, &Bs[inst * 512]);
    }
    __syncthreads();

    const int kc = lane >> 4;
    short8 af[4], bfr[4];
#pragma unroll
    for (int i = 0; i < 4; ++i) {
      const int row = wr * 64 + i * 16 + (lane & 15);
      const int ch = kc ^ ((row >> 1) & 3);
      af[i] = *reinterpret_cast<const short8*>(&As[row * 32 + ch * 8]);
    }
#pragma unroll
    for (int j = 0; j < 4; ++j) {
      const int row = wc * 64 + j * 16 + (lane & 15);
      const int ch = kc ^ ((row >> 1) & 3);
      bfr[j] = *reinterpret_cast<const short8*>(&Bs[row * 32 + ch * 8]);
    }
#pragma unroll
    for (int i = 0; i < 4; ++i)
#pragma unroll
      for (int j = 0; j < 4; ++j)
        acc[i][j] = __builtin_amdgcn_mfma_f32_16x16x32_bf16(af[i], bfr[j],
                                                            acc[i][j], 0, 0, 0);
    __syncthreads();
  }

  if constexpr (QUANT == 1) {
    float bv[4];
#pragma unroll
    for (int j = 0; j < 4; ++j) bv[j] = bias[wc * 64 + j * 16 + (lane & 15)];
    const int g = wc;
    u32* zq = (u32*)Cout;
#pragma unroll
    for (int i = 0; i < 4; ++i) {
#pragma unroll
      for (int r = 0; r < 4; ++r) {
        float o[4];
#pragma unroll
        for (int j = 0; j < 4; ++j) o[j] = acc[i][j][r] + bv[j];
        float am = fmaxf(fmaxf(fabsf(o[0]), fabsf(o[1])),
                         fmaxf(fabsf(o[2]), fabsf(o[3])));
#pragma unroll
        for (int mk = 1; mk < 16; mk <<= 1) am = fmaxf(am, __shfl_xor(am, mk));
        const float sinv = am > 0.f ? 127.f / am : 0.f;
        const float scv = am > 0.f ? am / 127.f : 0.f;
        const int q0 = __float2int_rn(o[0] * sinv) + 128;
        const int q1 = __float2int_rn(o[1] * sinv) + 128;
        const int q2 = __float2int_rn(o[2] * sinv) + 128;
        const int q3 = __float2int_rn(o[3] * sinv) + 128;
        const u32 dw = (q0 & 0xff) | ((q1 & 0xff) << 8) | ((q2 & 0xff) << 16) |
                       ((q3 & 0xff) << 24);
        const int row = bm + wr * 64 + i * 16 + (lane >> 4) * 4 + r;
        if (row < M) {
          zq[(size_t)row * 64 + g * 16 + (lane & 15)] = dw;
          if ((lane & 15) == 0) scales[(size_t)row * 4 + g] = scv;
        }
      }
    }
  } else {
    u16* C = (u16*)Cout;
#pragma unroll
    for (int i = 0; i < 4; ++i) {
#pragma unroll
      for (int j = 0; j < 4; ++j) {
        const int col = wc * 64 + j * 16 + (lane & 15);
        const float bv = bias[col];
#pragma unroll
        for (int r = 0; r < 4; ++r) {
          const int row = bm + wr * 64 + i * 16 + (lane >> 4) * 4 + r;
          if (row < M) {
            float o = fmaxf(acc[i][j][r] + bv, 0.f);
            C[(size_t)row * 256 + col] = f2bf(o);
          }
        }
      }
    }
  }
}

// ---------------------------------------------------------------------------
// 8-wave GEMM, A read directly as fp32 (reg-staged -> bf16 -> swizzled LDS).
// ---------------------------------------------------------------------------
__device__ __forceinline__ void gemm8_af32(
    int bx, const float* __restrict__ Af, const u16* __restrict__ Bt,
    const float* __restrict__ bias, u16* __restrict__ C, int M, int K,
    u16* As, u16* Bs) {
  const int tid = threadIdx.x;
  const int w = tid >> 6;
  const int lane = tid & 63;
  const int bm = bx * 128;
  const int wr = w >> 2;
  const int wc = w & 3;

  f32x4 acc[4][4];
#pragma unroll
  for (int i = 0; i < 4; ++i)
#pragma unroll
    for (int j = 0; j < 4; ++j) acc[i][j] = (f32x4)0.f;

  const int arow = tid >> 2;
  const int aq = tid & 3;
  int arg = bm + arow;
  if (arg > M - 1) arg = M - 1;
  const int asw = (arow >> 1) & 3;

  for (int k0 = 0; k0 < K; k0 += 32) {
#pragma unroll
    for (int s = 0; s < 2; ++s) {
      const int inst = w * 2 + s;
      const int row = inst * 16 + (lane >> 2);
      const int c = (lane & 3) ^ ((row >> 1) & 3);
      gload_lds16(Bt + (size_t)row * K + k0 + c * 8, &Bs[inst * 512]);
    }
    {
      const float4* src =
          reinterpret_cast<const float4*>(Af + (size_t)arg * K + k0 + aq * 8);
      const float4 v0 = src[0], v1 = src[1];
      short8 ch;
      ch[0] = (short)f2bf(v0.x); ch[1] = (short)f2bf(v0.y);
      ch[2] = (short)f2bf(v0.z); ch[3] = (short)f2bf(v0.w);
      ch[4] = (short)f2bf(v1.x); ch[5] = (short)f2bf(v1.y);
      ch[6] = (short)f2bf(v1.z); ch[7] = (short)f2bf(v1.w);
      reinterpret_cast<short8*>(As + arow * 32)[aq ^ asw] = ch;
    }
    __syncthreads();

    const int kc = lane >> 4;
    short8 af[4], bfr[4];
#pragma unroll
    for (int i = 0; i < 4; ++i) {
      const int row = wr * 64 + i * 16 + (lane & 15);
      const int ch = kc ^ ((row >> 1) & 3);
      af[i] = *reinterpret_cast<const short8*>(&As[row * 32 + ch * 8]);
    }
#pragma unroll
    for (int j = 0; j < 4; ++j) {
      const int row = wc * 64 + j * 16 + (lane & 15);
      const int ch = kc ^ ((row >> 1) & 3);
      bfr[j] = *reinterpret_cast<const short8*>(&Bs[row * 32 + ch * 8]);
    }
#pragma unroll
    for (int i = 0; i < 4; ++i)
#pragma unroll
      for (int j = 0; j < 4; ++j)
        acc[i][j] = __builtin_amdgcn_mfma_f32_16x16x32_bf16(af[i], bfr[j],
                                                            acc[i][j], 0, 0, 0);
    __syncthreads();
  }

#pragma unroll
  for (int i = 0; i < 4; ++i) {
#pragma unroll
    for (int j = 0; j < 4; ++j) {
      const int col = wc * 64 + j * 16 + (lane & 15);
      const float bv = bias[col];
#pragma unroll
      for (int r = 0; r < 4; ++r) {
        const int row = bm + wr * 64 + i * 16 + (lane >> 4) * 4 + r;
        if (row < M) {
          float o = fmaxf(acc[i][j][r] + bv, 0.f);
          C[(size_t)row * 256 + col] = f2bf(o);
        }
      }
    }
  }
}

// ---------------------------------------------------------------------------
// 4-wave GEMM (gemm4): BN=64, BIASED-uint8 out, per-row scale.
// ---------------------------------------------------------------------------
__global__ __launch_bounds__(256) void gemm4_q8(
    const u16* __restrict__ A, const u16* __restrict__ Bt,
    const float* __restrict__ bias, u32* __restrict__ zq,
    float* __restrict__ scales, int M, int K) {
  __shared__ __align__(16) u16 As[128 * 32];
  __shared__ __align__(16) u16 Bs[64 * 32];
  const int tid = threadIdx.x;
  const int w = tid >> 6;
  const int lane = tid & 63;
  const int bm = blockIdx.x * 128;

  f32x4 acc[2][4];
#pragma unroll
  for (int i = 0; i < 2; ++i)
#pragma unroll
    for (int j = 0; j < 4; ++j) acc[i][j] = (f32x4)0.f;

  for (int k0 = 0; k0 < K; k0 += 32) {
#pragma unroll
    for (int s = 0; s < 2; ++s) {
      const int inst = w * 2 + s;
      const int row = inst * 16 + (lane >> 2);
      int rg = bm + row;
      if (rg > M - 1) rg = M - 1;
      const int c = (lane & 3) ^ ((row >> 1) & 3);
      gload_lds16(A + (size_t)rg * K + k0 + c * 8, &As[inst * 512]);
    }
    {
      const int row = w * 16 + (lane >> 2);
      const int c = (lane & 3) ^ ((row >> 1) & 3);
      gload_lds16(Bt + (size_t)row * K + k0 + c * 8, &Bs[w * 512]);
    }
    __syncthreads();

    const int kc = lane >> 4;
    short8 af[2], bfr[4];
#pragma unroll
    for (int i = 0; i < 2; ++i) {
      const int row = w * 32 + i * 16 + (lane & 15);
      const int ch = kc ^ ((row >> 1) & 3);
      af[i] = *reinterpret_cast<const short8*>(&As[row * 32 + ch * 8]);
    }
#pragma unroll
    for (int j = 0; j < 4; ++j) {
      const int row = j * 16 + (lane & 15);
      const int ch = kc ^ ((row >> 1) & 3);
      bfr[j] = *reinterpret_cast<const short8*>(&Bs[row * 32 + ch * 8]);
    }
#pragma unroll
    for (int i = 0; i < 2; ++i)
#pragma unroll
      for (int j = 0; j < 4; ++j)
        acc[i][j] = __builtin_amdgcn_mfma_f32_16x16x32_bf16(af[i], bfr[j],
                                                            acc[i][j], 0, 0, 0);
    __syncthreads();
  }

  float bv[4];
#pragma unroll
  for (int j = 0; j < 4; ++j) bv[j] = bias[j * 16 + (lane & 15)];
#pragma unroll
  for (int i = 0; i < 2; ++i) {
#pragma unroll
    for (int r = 0; r < 4; ++r) {
      float o[4];
#pragma unroll
      for (int j = 0; j < 4; ++j) o[j] = acc[i][j][r] + bv[j];
      float am = fmaxf(fmaxf(fabsf(o[0]), fabsf(o[1])),
                       fmaxf(fabsf(o[2]), fabsf(o[3])));
#pragma unroll
      for (int mk = 1; mk < 16; mk <<= 1) am = fmaxf(am, __shfl_xor(am, mk));
      const float sinv = am > 0.f ? 127.f / am : 0.f;
      const float scv = am > 0.f ? am / 127.f : 0.f;
      const int q0 = __float2int_rn(o[0] * sinv) + 128;
      const int q1 = __float2int_rn(o[1] * sinv) + 128;
      const int q2 = __float2int_rn(o[2] * sinv) + 128;
      const int q3 = __float2int_rn(o[3] * sinv) + 128;
      const u32 dw = (q0 & 0xff) | ((q1 & 0xff) << 8) | ((q2 & 0xff) << 16) |
                     ((q3 & 0xff) << 24);
      const int row = bm + w * 32 + i * 16 + (lane >> 4) * 4 + r;
      if (row < M) {
        zq[(size_t)row * 16 + (lane & 15)] = dw;
        if ((lane & 15) == 0) scales[row] = scv;
      }
    }
  }
}

// ---------------------------------------------------------------------------
// L1 prep: weight transposes | p1 bucket histogram
// ---------------------------------------------------------------------------
__global__ __launch_bounds__(256) void prep(
    const float* __restrict__ W1a, const float* __restrict__ W1b,
    const float* __restrict__ Wf, const float* __restrict__ W2,
    u16* __restrict__ W1at, u16* __restrict__ W1bt, u16* __restrict__ Wft,
    u16* __restrict__ W2t, const int* __restrict__ rows,
    int* __restrict__ cnt) {
  __shared__ int hsh[NBUCK];
  const int b = blockIdx.x;
  const int tid = threadIdx.x;
  if (b < WT_BLKS) {
    const int i = b * 256 + tid;
    if (i < 65536) {
      const int n = i >> 8, k = i & 255;
      W1at[i] = f2bf(W1a[k * 256 + n]);
    } else if (i < 98304) {
      const int t = i - 65536;
      const int n = t >> 7, k = t & 127;
      W1bt[t] = f2bf(W1b[k * 256 + n]);
    } else if (i < 163840) {
      const int t = i - 98304;
      const int n = t >> 8, k = t & 255;
      Wft[t] = f2bf(Wf[k * 256 + n]);
    } else if (i < 180224) {
      const int t = i - 163840;
      const int n = t >> 8, p = t & 255;
      const int f = ((p >> 6) << 6) + ((p & 3) << 4) + ((p >> 2) & 15);
      W2t[t] = f2bf(W2[f * 64 + n]);
    }
  } else {
    const int blk = b - WT_BLKS;
    for (int i = tid; i < NBUCK; i += 256) hsh[i] = 0;
    __syncthreads();
    const int s = blk * CHUNK;
    const int e = s + CHUNK;
    for (int i = s + tid; i < e; i += 256) atomicAdd(&hsh[rows[i] >> 6], 1);
    __syncthreads();
    for (int i = tid; i < NBUCK; i += 256) cnt[i * PBLK + blk] = hsh[i];
  }
}

// ---------------------------------------------------------------------------
// L2 (512 thr): gemm1 (fp32 A) | gemm2 (fp32 A) | s1 per-bucket scan
// ---------------------------------------------------------------------------
__global__ __launch_bounds__(512) void gemm12_s1(
    const float* __restrict__ xa, const u16* __restrict__ W1at,
    const float* __restrict__ b1a, const float* __restrict__ xb,
    const u16* __restrict__ W1bt, const float* __restrict__ b1b,
    u16* __restrict__ h, int* __restrict__ cnt, int* __restrict__ btot) {
  __shared__ __align__(16) u16 As[128 * 32];
  __shared__ __align__(16) u16 Bs[256 * 32];
  const int b = blockIdx.x;
  if (b < G1_BLKS) {
    gemm8_af32(b, xa, W1at, b1a, h, NA, 256, As, Bs);
  } else if (b < G1_BLKS + G2_BLKS) {
    gemm8_af32(b - G1_BLKS, xb, W1bt, b1b, h + (size_t)NA * NHID, NB, 128, As,
               Bs);
  } else {
    int* lds = (int*)As;
    const int bu = b - (G1_BLKS + G2_BLKS);
    const int t = threadIdx.x;
    const int v = (t < PBLK) ? cnt[bu * PBLK + t] : 0;
    lds[t] = v;
    __syncthreads();
#pragma unroll
    for (int off = 1; off < PBLK; off <<= 1) {
      const int x = (t >= off) ? lds[t - off] : 0;
      __syncthreads();
      lds[t] += x;
      __syncthreads();
    }
    if (t < PBLK) cnt[bu * PBLK + t] = lds[t] - v;
    if (t == PBLK - 1) btot[bu] = lds[t];
  }
}

// ---------------------------------------------------------------------------
// L3a (512 thr): gemm3 first half | s2 scan (global bstart) | p3 scatter
// ---------------------------------------------------------------------------
__global__ __launch_bounds__(512) void gemm3a_s2_p3(
    const u16* __restrict__ h, const u16* __restrict__ Wft,
    const float* __restrict__ bfv, u32* __restrict__ zq,
    float* __restrict__ zscale, const int* __restrict__ btot,
    int* __restrict__ bstart, const int* __restrict__ rows,
    const int* __restrict__ cols, const float* __restrict__ vals,
    const int* __restrict__ cnt, int2* __restrict__ edges) {
  __shared__ __align__(16) u16 As[128 * 32];
  __shared__ __align__(16) u16 Bs[256 * 32];
  const int b = blockIdx.x;
  const int t = threadIdx.x;
  if (b < G3A) {
    gemm8_body<1>(b, h, Wft, bfv, zq, zscale, NN, 256, As, Bs);
  } else if (b == G3A) {
    int* lds = (int*)As;
    int carry = 0;
    for (int base = 0; base < NBUCK; base += 512) {
      const int i = base + t;
      const int v = (i < NBUCK) ? btot[i] : 0;
      lds[t] = v;
      __syncthreads();
#pragma unroll
      for (int off = 1; off < 512; off <<= 1) {
        const int x = (t >= off) ? lds[t - off] : 0;
        __syncthreads();
        lds[t] += x;
        __syncthreads();
      }
      const int excl = lds[t] - v;
      const int tot = lds[511];
      if (i < NBUCK) bstart[i] = carry + excl;
      __syncthreads();
      carry += tot;
    }
    if (t == 0) bstart[NBUCK] = NE;
  } else {
    // p3: local bstart scan (independent of s2), then scatter chunk
    const int blk = b - (G3A + 1);
    int* lbs = (int*)As;
    int* tmp = (int*)Bs;
    int carry = 0;
    for (int base = 0; base < NBUCK; base += 512) {
      const int i = base + t;
      const int v = (i < NBUCK) ? btot[i] : 0;
      tmp[t] = v;
      __syncthreads();
#pragma unroll
      for (int off = 1; off < 512; off <<= 1) {
        const int x = (t >= off) ? tmp[t - off] : 0;
        __syncthreads();
        tmp[t] += x;
        __syncthreads();
      }
      if (i < NBUCK) lbs[i] = carry + tmp[t] - v;
      const int tot = tmp[511];
      __syncthreads();
      carry += tot;
    }
    for (int bu = t; bu < NBUCK; bu += 512) lbs[bu] += cnt[bu * PBLK + blk];
    __syncthreads();
    const int s = blk * CHUNK;
    const int e = s + CHUNK;
    for (int i = s + t; i < e; i += 512) {
      const int r = rows[i];
      const int pos = atomicAdd(&lbs[r >> 6], 1);
      edges[pos] =
          make_int2(cols[i] | ((r & 63) << 17), __float_as_int(vals[i]));
    }
  }
}

// ---------------------------------------------------------------------------
// L3b (512 thr): gemm3 second half | per-bucket sort -> 4B records + rptr
// edges2 word = col(17b) | f16(val) sans sign (15b) << 17.
// ---------------------------------------------------------------------------
__global__ __launch_bounds__(512) void gemm3b_sort(
    const u16* __restrict__ h, const u16* __restrict__ Wft,
    const float* __restrict__ bfv, u32* __restrict__ zq,
    float* __restrict__ zscale, const int* __restrict__ bstart,
    const int2* __restrict__ edges, u32* __restrict__ edges2,
    int* __restrict__ rptr) {
  __shared__ __align__(16) u16 As[128 * 32];
  __shared__ __align__(16) u16 Bs[256 * 32];
  __shared__ int hist[RPB];
  __shared__ int sc[RPB];
  __shared__ int cur[RPB];
  const int b = blockIdx.x;
  const int t = threadIdx.x;
  if (b < G3B) {
    gemm8_body<1>(b + G3A, h, Wft, bfv, zq, zscale, NN, 256, As, Bs);
  } else {
    const int bu = b - G3B;
    const int s = bstart[bu], e = bstart[bu + 1];
    if (t < RPB) hist[t] = 0;
    __syncthreads();
    for (int i = s + t; i < e; i += 512)
      atomicAdd(&hist[(edges[i].x >> 17) & 63], 1);
    __syncthreads();
    const int hv = (t < RPB) ? hist[t] : 0;
    if (t < RPB) sc[t] = hv;
    __syncthreads();
#pragma unroll
    for (int off = 1; off < RPB; off <<= 1) {
      const int x = (t >= off && t < RPB) ? sc[t - off] : 0;
      __syncthreads();
      if (t < RPB) sc[t] += x;
      __syncthreads();
    }
    if (t < RPB) {
      const int base = s + sc[t] - hv;
      cur[t] = base;
      const int grow = bu * RPB + t;
      if (grow < NN) rptr[grow] = base;
    }
    if (bu == 0 && t == 0) rptr[NN] = NE;
    __syncthreads();
    for (int i = s + t; i < e; i += 512) {
      const int2 ed = edges[i];
      const int lr = (ed.x >> 17) & 63;
      const int pos = atomicAdd(&cur[lr], 1);
      edges2[pos] = (u32)(ed.x & 0x1FFFF) |
                    ((u32)f2h(__int_as_float(ed.y)) << 17);
    }
  }
}

// ---------------------------------------------------------------------------
// L4: CSR SpMM width 256, biased-uint8 payload, 4B edges, relu+bf16 out.
// Unpack via v_cvt_f32_ubyte (compiler-folded); -128 bias folded into S.
// ---------------------------------------------------------------------------
__global__ __launch_bounds__(256) void spmm256_q8(
    const int* __restrict__ ptr, const u32* __restrict__ edges,
    const u32* __restrict__ Zq, const float* __restrict__ scales,
    u16* __restrict__ Yb) {
  const int wid = (int)((blockIdx.x * (size_t)256 + threadIdx.x) >> 6);
  const int lane = threadIdx.x & 63;
  if (wid >= NN) return;
  const int s = ptr[wid], e = ptr[wid + 1];
  const int gsel = lane >> 4;
  float a0 = 0.f, a1 = 0.f, a2 = 0.f, a3 = 0.f, S = 0.f;
  int j = s;
  for (; j + 7 < e; j += 8) {
    u32 ed[8];
#pragma unroll
    for (int q = 0; q < 8; ++q) ed[q] = edges[j + q];
    u32 dw[8];
    float sc[8];
#pragma unroll
    for (int q = 0; q < 8; ++q) {
      const int c = ed[q] & 0x1FFFF;
      dw[q] = Zq[(size_t)c * 64 + lane];
      sc[q] = scales[(size_t)c * 4 + gsel];
    }
#pragma unroll
    for (int q = 0; q < 8; ++q) {
      const float vs = h2f(ed[q] >> 17) * sc[q];
      S += vs;
      a0 += vs * (float)(dw[q] & 0xffu);
      a1 += vs * (float)((dw[q] >> 8) & 0xffu);
      a2 += vs * (float)((dw[q] >> 16) & 0xffu);
      a3 += vs * (float)(dw[q] >> 24);
    }
  }
  for (; j < e; ++j) {
    const u32 ed = edges[j];
    const int c = ed & 0x1FFFF;
    const u32 dw = Zq[(size_t)c * 64 + lane];
    const float vs = h2f(ed >> 17) * scales[(size_t)c * 4 + gsel];
    S += vs;
    a0 += vs * (float)(dw & 0xffu);
    a1 += vs * (float)((dw >> 8) & 0xffu);
    a2 += vs * (float)((dw >> 16) & 0xffu);
    a3 += vs * (float)(dw >> 24);
  }
  const float corr = 128.f * S;
  ushort4 o;
  o.x = f2bf(fmaxf(a0 - corr, 0.f));
  o.y = f2bf(fmaxf(a1 - corr, 0.f));
  o.z = f2bf(fmaxf(a2 - corr, 0.f));
  o.w = f2bf(fmaxf(a3 - corr, 0.f));
  reinterpret_cast<ushort4*>(Yb + (size_t)wid * 256)[lane] = o;
}

// ---------------------------------------------------------------------------
// L6: CSR SpMM width 64, biased-uint8 payload, 4B edges, fp32 out.
// ---------------------------------------------------------------------------
__global__ __launch_bounds__(256) void spmm64_q8(
    const int* __restrict__ ptr, const u32* __restrict__ edges,
    const u32* __restrict__ Z2q, const float* __restrict__ zsc2,
    float* __restrict__ Y) {
  const int wid = (int)((blockIdx.x * (size_t)256 + threadIdx.x) >> 6);
  const int lane = threadIdx.x & 63;
  if (wid >= NN) return;
  const int s = ptr[wid], e = ptr[wid + 1];
  const int dwi = lane & 15;
  const int bsh = (lane >> 4) * 8;
  float acc = 0.f, S = 0.f;
  int j = s;
  for (; j + 7 < e; j += 8) {
    u32 ed[8];
#pragma unroll
    for (int q = 0; q < 8; ++q) ed[q] = edges[j + q];
    u32 dw[8];
    float sc[8];
#pragma unroll
    for (int q = 0; q < 8; ++q) {
      const int c = ed[q] & 0x1FFFF;
      dw[q] = Z2q[(size_t)c * 16 + dwi];
      sc[q] = zsc2[c];
    }
#pragma unroll
    for (int q = 0; q < 8; ++q) {
      const float vs = h2f(ed[q] >> 17) * sc[q];
      S += vs;
      acc += vs * (float)((dw[q] >> bsh) & 0xffu);
    }
  }
  for (; j < e; ++j) {
    const u32 ed = edges[j];
    const int c = ed & 0x1FFFF;
    const float vs = h2f(ed >> 17) * zsc2[c];
    S += vs;
    acc += vs * (float)((Z2q[(size_t)c * 16 + dwi] >> bsh) & 0xffu);
  }
  Y[(size_t)wid * 64 + lane] = acc - 128.f * S;
}

extern "C" void kernel_launch(void* const* d_in, const int* in_sizes, int n_in,
                              void* d_out, int out_size, void* d_ws,
                              size_t ws_size, hipStream_t stream) {
  const float* x_a  = (const float*)d_in[0];
  const float* x_b  = (const float*)d_in[1];
  const int*   rows = (const int*)d_in[2];
  const int*   cols = (const int*)d_in[3];
  const float* vals = (const float*)d_in[4];
  const float* W1a  = (const float*)d_in[5];
  const float* b1a  = (const float*)d_in[6];
  const float* W1b  = (const float*)d_in[7];
  const float* b1b  = (const float*)d_in[8];
  const float* Wf   = (const float*)d_in[9];
  const float* bf   = (const float*)d_in[10];
  const float* W2   = (const float*)d_in[11];
  const float* b2   = (const float*)d_in[12];
  float* out = (float*)d_out;

  // workspace (~130 MB)
  char* p = (char*)d_ws;
  u16* h    = (u16*)p;  p += (size_t)NN * NHID * 2;   // 51.2MB (h, later s1b)
  u32* zq   = (u32*)p;  p += (size_t)NN * 64 * 4;     // 25.6MB uint8 z
  float* zscale = (float*)p; p += (size_t)NN * 4 * 4; // 1.6MB
  u32* z2q  = (u32*)p;  p += (size_t)NN * 16 * 4;     // 6.4MB uint8 z2
  float* zsc2 = (float*)p; p += (size_t)NN * 4;       // 0.4MB
  u32* edges2 = (u32*)p;  p += (size_t)NE * 4;        // 12.8MB (4B records)
  u16* W1at = (u16*)p;  p += 256 * 256 * 2;
  u16* W1bt = (u16*)p;  p += 256 * 128 * 2;
  u16* Wft  = (u16*)p;  p += 256 * 256 * 2;
  u16* W2t  = (u16*)p;  p += 64 * 256 * 2;
  int2* edges = (int2*)p; p += (size_t)NE * 8;        // 25.6MB
  int* cnt    = (int*)p;  p += (size_t)NBUCK * PBLK * 4;
  int* btot   = (int*)p;  p += (size_t)((NBUCK + 3) & ~3) * 4;
  int* bstart = (int*)p;  p += (size_t)((NBUCK + 4) & ~3) * 4;
  int* rptr   = (int*)p;  p += (size_t)(NN + 4) * 4;
  u16* s1b = h;

  // L1: weight transposes | p1 histogram
  prep<<<WT_BLKS + PBLK, 256, 0, stream>>>(W1a, W1b, Wf, W2, W1at, W1bt, Wft,
                                           W2t, rows, cnt);

  // L2: gemm1 | gemm2 (fp32 A, BN=256 single-pass) | s1 scan
  gemm12_s1<<<G1_BLKS + G2_BLKS + NBUCK, 512, 0, stream>>>(
      x_a, W1at, b1a, x_b, W1bt, b1b, h, cnt, btot);

  // L3a: gemm3 first half | s2 | p3 scatter
  gemm3a_s2_p3<<<G3A + 1 + PBLK, 512, 0, stream>>>(
      h, Wft, bf, zq, zscale, btot, bstart, rows, cols, vals, cnt, edges);

  // L3b: gemm3 second half | per-bucket row sort -> 4B records
  gemm3b_sort<<<G3B + NBUCK, 512, 0, stream>>>(h, Wft, bf, zq, zscale, bstart,
                                               edges, edges2, rptr);

  // L4: s1b = bf16(relu(spmm(zq)))  (permuted feature order)
  spmm256_q8<<<(NN * 64 + 255) / 256, 256, 0, stream>>>(rptr, edges2, zq,
                                                        zscale, s1b);
  // L5: z2q = uint8(s1b @ W2t^T + b2), per-row scale
  gemm4_q8<<<G3_BLKS, 256, 0, stream>>>(s1b, W2t, b2, z2q, zsc2, NN, 256);
  // L6: out = spmm(z2q)
  spmm64_q8<<<(NN * 64 + 255) / 256, 256, 0, stream>>>(rptr, edges2, z2q,
                                                       zsc2, out);
}

// Round 15
// 422.536 us; speedup vs baseline: 1.0034x; 1.0034x over previous
//
#include <hip/hip_runtime.h>

#define NN 100000
#define NE 3200000
#define NA 60000
#define NB 40000
#define NHID 256
#define NOUT 64

#define RPB 64                    // rows per bucket
#define NBUCK 1563                // ceil(NN/64)
#define PBLK 256                  // partition blocks
#define CHUNK 12500               // NE / PBLK (exact)

#define WT_BLKS 704               // 180224 / 256
#define G1_BLKS 469               // ceil(NA/128), BN=256 single pass
#define G2_BLKS 313               // ceil(NB/128)
#define G3_BLKS 782               // ceil(NN/128)
#define G3A 391                   // gemm3 first half (rides with s2|p3)
#define G3B 391                   // gemm3 second half (rides with sort)

typedef unsigned short u16;
typedef unsigned int u32;
typedef __attribute__((ext_vector_type(8))) short short8;
typedef __attribute__((ext_vector_type(4))) float f32x4;

__device__ __forceinline__ float bf2f(u16 u) {
  return __uint_as_float(((u32)u) << 16);
}
__device__ __forceinline__ u16 f2bf(float f) {
  u32 u = __float_as_uint(f);
  u32 r = (u + 0x7fffu + ((u >> 16) & 1u)) >> 16;  // RNE
  return (u16)r;
}
__device__ __forceinline__ u16 f2h(float f) {   // f32 -> f16 bits (RNE)
  _Float16 h = (_Float16)f;
  u16 r;
  __builtin_memcpy(&r, &h, 2);
  return r;
}
__device__ __forceinline__ float h2f(u32 b15) { // 15-bit f16 (sign=0) -> f32
  u16 hb = (u16)b15;
  _Float16 h;
  __builtin_memcpy(&h, &hb, 2);
  return (float)h;
}

__device__ __forceinline__ void gload_lds16(const void* gsrc, void* ldst) {
  __builtin_amdgcn_global_load_lds(
      (const __attribute__((address_space(1))) void*)gsrc,
      (__attribute__((address_space(3))) void*)ldst, 16, 0, 0);
}

// ---------------------------------------------------------------------------
// 8-wave GEMM body, BK=64 (2 barriers per 64 K-elems, 32 MFMA between).
// BM=128, BN=N=256, 512 threads (2x4 waves, 64x64 tiles).
// LDS: As[128][64] u16 (16KB), Bs[256][64] u16 (32KB). Chunk swizzle:
// LDS chunk c (8 u16) of row holds global chunk c^(row&7) (involution).
// QUANT=0: relu+bf16 out. QUANT=1: BIASED-uint8 out (q+128),
// per-row-per-64col scale, lane-major pack.
// ---------------------------------------------------------------------------
template <int QUANT>
__device__ __forceinline__ void gemm8_body(
    int bx, const u16* __restrict__ A, const u16* __restrict__ Bt,
    const float* __restrict__ bias, void* __restrict__ Cout,
    float* __restrict__ scales, int M, int K, u16* As, u16* Bs) {
  const int tid = threadIdx.x;
  const int w = tid >> 6;
  const int lane = tid & 63;
  const int bm = bx * 128;
  const int wr = w >> 2;   // 0..1
  const int wc = w & 3;    // 0..3

  f32x4 acc[4][4];
#pragma unroll
  for (int i = 0; i < 4; ++i)
#pragma unroll
    for (int j = 0; j < 4; ++j) acc[i][j] = (f32x4)0.f;

  for (int k0 = 0; k0 < K; k0 += 64) {
    // A tile [128][64]: 16 insts (1KB each, 8 rows), 2 per wave
#pragma unroll
    for (int s = 0; s < 2; ++s) {
      const int inst = w * 2 + s;
      const int row = inst * 8 + (lane >> 3);
      int rg = bm + row;
      if (rg > M - 1) rg = M - 1;
      const int c = (lane & 7) ^ (row & 7);
      gload_lds16(A + (size_t)rg * K + k0 + c * 8, &As[inst * 512]);
    }
    // B tile [256][64]: 32 insts, 4 per wave
#pragma unroll
    for (int s = 0; s < 4; ++s) {
      const int inst = w * 4 + s;
      const int row = inst * 8 + (lane >> 3);
      const int c = (lane & 7) ^ (row & 7);
      gload_lds16(Bt + (size_t)row * K + k0 + c * 8, &Bs[inst * 512]);
    }
    __syncthreads();

    const int kc = lane >> 4;
#pragma unroll
    for (int ksub = 0; ksub < 2; ++ksub) {
      short8 af[4], bfr[4];
#pragma unroll
      for (int i = 0; i < 4; ++i) {
        const int row = wr * 64 + i * 16 + (lane & 15);
        const int ch = (ksub * 4 + kc) ^ (row & 7);
        af[i] = *reinterpret_cast<const short8*>(&As[row * 64 + ch * 8]);
      }
#pragma unroll
      for (int j = 0; j < 4; ++j) {
        const int row = wc * 64 + j * 16 + (lane & 15);
        const int ch = (ksub * 4 + kc) ^ (row & 7);
        bfr[j] = *reinterpret_cast<const short8*>(&Bs[row * 64 + ch * 8]);
      }
#pragma unroll
      for (int i = 0; i < 4; ++i)
#pragma unroll
        for (int j = 0; j < 4; ++j)
          acc[i][j] = __builtin_amdgcn_mfma_f32_16x16x32_bf16(
              af[i], bfr[j], acc[i][j], 0, 0, 0);
    }
    __syncthreads();
  }

  if constexpr (QUANT == 1) {
    float bv[4];
#pragma unroll
    for (int j = 0; j < 4; ++j) bv[j] = bias[wc * 64 + j * 16 + (lane & 15)];
    const int g = wc;
    u32* zq = (u32*)Cout;
#pragma unroll
    for (int i = 0; i < 4; ++i) {
#pragma unroll
      for (int r = 0; r < 4; ++r) {
        float o[4];
#pragma unroll
        for (int j = 0; j < 4; ++j) o[j] = acc[i][j][r] + bv[j];
        float am = fmaxf(fmaxf(fabsf(o[0]), fabsf(o[1])),
                         fmaxf(fabsf(o[2]), fabsf(o[3])));
#pragma unroll
        for (int mk = 1; mk < 16; mk <<= 1) am = fmaxf(am, __shfl_xor(am, mk));
        const float sinv = am > 0.f ? 127.f / am : 0.f;
        const float scv = am > 0.f ? am / 127.f : 0.f;
        const int q0 = __float2int_rn(o[0] * sinv) + 128;
        const int q1 = __float2int_rn(o[1] * sinv) + 128;
        const int q2 = __float2int_rn(o[2] * sinv) + 128;
        const int q3 = __float2int_rn(o[3] * sinv) + 128;
        const u32 dw = (q0 & 0xff) | ((q1 & 0xff) << 8) | ((q2 & 0xff) << 16) |
                       ((q3 & 0xff) << 24);
        const int row = bm + wr * 64 + i * 16 + (lane >> 4) * 4 + r;
        if (row < M) {
          zq[(size_t)row * 64 + g * 16 + (lane & 15)] = dw;
          if ((lane & 15) == 0) scales[(size_t)row * 4 + g] = scv;
        }
      }
    }
  } else {
    u16* C = (u16*)Cout;
#pragma unroll
    for (int i = 0; i < 4; ++i) {
#pragma unroll
      for (int j = 0; j < 4; ++j) {
        const int col = wc * 64 + j * 16 + (lane & 15);
        const float bv = bias[col];
#pragma unroll
        for (int r = 0; r < 4; ++r) {
          const int row = bm + wr * 64 + i * 16 + (lane >> 4) * 4 + r;
          if (row < M) {
            float o = fmaxf(acc[i][j][r] + bv, 0.f);
            C[(size_t)row * 256 + col] = f2bf(o);
          }
        }
      }
    }
  }
}

// ---------------------------------------------------------------------------
// 8-wave GEMM BK=64, A read directly as fp32 (reg-staged -> bf16 -> swizzled
// LDS). Thread covers row=tid>>2, chunks {2aq, 2aq+1} (16 fp32 = 64B read).
// ---------------------------------------------------------------------------
__device__ __forceinline__ void gemm8_af32(
    int bx, const float* __restrict__ Af, const u16* __restrict__ Bt,
    const float* __restrict__ bias, u16* __restrict__ C, int M, int K,
    u16* As, u16* Bs) {
  const int tid = threadIdx.x;
  const int w = tid >> 6;
  const int lane = tid & 63;
  const int bm = bx * 128;
  const int wr = w >> 2;
  const int wc = w & 3;

  f32x4 acc[4][4];
#pragma unroll
  for (int i = 0; i < 4; ++i)
#pragma unroll
    for (int j = 0; j < 4; ++j) acc[i][j] = (f32x4)0.f;

  const int arow = tid >> 2;
  const int aq = tid & 3;
  int arg = bm + arow;
  if (arg > M - 1) arg = M - 1;
  const int asw = arow & 7;

  for (int k0 = 0; k0 < K; k0 += 64) {
#pragma unroll
    for (int s = 0; s < 4; ++s) {
      const int inst = w * 4 + s;
      const int row = inst * 8 + (lane >> 3);
      const int c = (lane & 7) ^ (row & 7);
      gload_lds16(Bt + (size_t)row * K + k0 + c * 8, &Bs[inst * 512]);
    }
    {
      const float4* src =
          reinterpret_cast<const float4*>(Af + (size_t)arg * K + k0 + aq * 16);
      const float4 v0 = src[0], v1 = src[1], v2 = src[2], v3 = src[3];
      short8 lo, hi;
      lo[0] = (short)f2bf(v0.x); lo[1] = (short)f2bf(v0.y);
      lo[2] = (short)f2bf(v0.z); lo[3] = (short)f2bf(v0.w);
      lo[4] = (short)f2bf(v1.x); lo[5] = (short)f2bf(v1.y);
      lo[6] = (short)f2bf(v1.z); lo[7] = (short)f2bf(v1.w);
      hi[0] = (short)f2bf(v2.x); hi[1] = (short)f2bf(v2.y);
      hi[2] = (short)f2bf(v2.z); hi[3] = (short)f2bf(v2.w);
      hi[4] = (short)f2bf(v3.x); hi[5] = (short)f2bf(v3.y);
      hi[6] = (short)f2bf(v3.z); hi[7] = (short)f2bf(v3.w);
      short8* dst = reinterpret_cast<short8*>(As + arow * 64);
      dst[(aq * 2) ^ asw] = lo;
      dst[(aq * 2 + 1) ^ asw] = hi;
    }
    __syncthreads();

    const int kc = lane >> 4;
#pragma unroll
    for (int ksub = 0; ksub < 2; ++ksub) {
      short8 af[4], bfr[4];
#pragma unroll
      for (int i = 0; i < 4; ++i) {
        const int row = wr * 64 + i * 16 + (lane & 15);
        const int ch = (ksub * 4 + kc) ^ (row & 7);
        af[i] = *reinterpret_cast<const short8*>(&As[row * 64 + ch * 8]);
      }
#pragma unroll
      for (int j = 0; j < 4; ++j) {
        const int row = wc * 64 + j * 16 + (lane & 15);
        const int ch = (ksub * 4 + kc) ^ (row & 7);
        bfr[j] = *reinterpret_cast<const short8*>(&Bs[row * 64 + ch * 8]);
      }
#pragma unroll
      for (int i = 0; i < 4; ++i)
#pragma unroll
        for (int j = 0; j < 4; ++j)
          acc[i][j] = __builtin_amdgcn_mfma_f32_16x16x32_bf16(
              af[i], bfr[j], acc[i][j], 0, 0, 0);
    }
    __syncthreads();
  }

#pragma unroll
  for (int i = 0; i < 4; ++i) {
#pragma unroll
    for (int j = 0; j < 4; ++j) {
      const int col = wc * 64 + j * 16 + (lane & 15);
      const float bv = bias[col];
#pragma unroll
      for (int r = 0; r < 4; ++r) {
        const int row = bm + wr * 64 + i * 16 + (lane >> 4) * 4 + r;
        if (row < M) {
          float o = fmaxf(acc[i][j][r] + bv, 0.f);
          C[(size_t)row * 256 + col] = f2bf(o);
        }
      }
    }
  }
}

// ---------------------------------------------------------------------------
// 4-wave GEMM (gemm4), BK=64: BN=64, BIASED-uint8 out, per-row scale.
// LDS: As 16KB, Bs 8KB.
// ---------------------------------------------------------------------------
__global__ __launch_bounds__(256) void gemm4_q8(
    const u16* __restrict__ A, const u16* __restrict__ Bt,
    const float* __restrict__ bias, u32* __restrict__ zq,
    float* __restrict__ scales, int M, int K) {
  __shared__ __align__(16) u16 As[128 * 64];
  __shared__ __align__(16) u16 Bs[64 * 64];
  const int tid = threadIdx.x;
  const int w = tid >> 6;
  const int lane = tid & 63;
  const int bm = blockIdx.x * 128;

  f32x4 acc[2][4];
#pragma unroll
  for (int i = 0; i < 2; ++i)
#pragma unroll
    for (int j = 0; j < 4; ++j) acc[i][j] = (f32x4)0.f;

  for (int k0 = 0; k0 < K; k0 += 64) {
#pragma unroll
    for (int s = 0; s < 4; ++s) {
      const int inst = w * 4 + s;
      const int row = inst * 8 + (lane >> 3);
      int rg = bm + row;
      if (rg > M - 1) rg = M - 1;
      const int c = (lane & 7) ^ (row & 7);
      gload_lds16(A + (size_t)rg * K + k0 + c * 8, &As[inst * 512]);
    }
#pragma unroll
    for (int s = 0; s < 2; ++s) {
      const int inst = w * 2 + s;
      const int row = inst * 8 + (lane >> 3);
      const int c = (lane & 7) ^ (row & 7);
      gload_lds16(Bt + (size_t)row * K + k0 + c * 8, &Bs[inst * 512]);
    }
    __syncthreads();

    const int kc = lane >> 4;
#pragma unroll
    for (int ksub = 0; ksub < 2; ++ksub) {
      short8 af[2], bfr[4];
#pragma unroll
      for (int i = 0; i < 2; ++i) {
        const int row = w * 32 + i * 16 + (lane & 15);
        const int ch = (ksub * 4 + kc) ^ (row & 7);
        af[i] = *reinterpret_cast<const short8*>(&As[row * 64 + ch * 8]);
      }
#pragma unroll
      for (int j = 0; j < 4; ++j) {
        const int row = j * 16 + (lane & 15);
        const int ch = (ksub * 4 + kc) ^ (row & 7);
        bfr[j] = *reinterpret_cast<const short8*>(&Bs[row * 64 + ch * 8]);
      }
#pragma unroll
      for (int i = 0; i < 2; ++i)
#pragma unroll
        for (int j = 0; j < 4; ++j)
          acc[i][j] = __builtin_amdgcn_mfma_f32_16x16x32_bf16(
              af[i], bfr[j], acc[i][j], 0, 0, 0);
    }
    __syncthreads();
  }

  float bv[4];
#pragma unroll
  for (int j = 0; j < 4; ++j) bv[j] = bias[j * 16 + (lane & 15)];
#pragma unroll
  for (int i = 0; i < 2; ++i) {
#pragma unroll
    for (int r = 0; r < 4; ++r) {
      float o[4];
#pragma unroll
      for (int j = 0; j < 4; ++j) o[j] = acc[i][j][r] + bv[j];
      float am = fmaxf(fmaxf(fabsf(o[0]), fabsf(o[1])),
                       fmaxf(fabsf(o[2]), fabsf(o[3])));
#pragma unroll
      for (int mk = 1; mk < 16; mk <<= 1) am = fmaxf(am, __shfl_xor(am, mk));
      const float sinv = am > 0.f ? 127.f / am : 0.f;
      const float scv = am > 0.f ? am / 127.f : 0.f;
      const int q0 = __float2int_rn(o[0] * sinv) + 128;
      const int q1 = __float2int_rn(o[1] * sinv) + 128;
      const int q2 = __float2int_rn(o[2] * sinv) + 128;
      const int q3 = __float2int_rn(o[3] * sinv) + 128;
      const u32 dw = (q0 & 0xff) | ((q1 & 0xff) << 8) | ((q2 & 0xff) << 16) |
                     ((q3 & 0xff) << 24);
      const int row = bm + w * 32 + i * 16 + (lane >> 4) * 4 + r;
      if (row < M) {
        zq[(size_t)row * 16 + (lane & 15)] = dw;
        if ((lane & 15) == 0) scales[row] = scv;
      }
    }
  }
}

// ---------------------------------------------------------------------------
// L1 prep: weight transposes | p1 bucket histogram
// ---------------------------------------------------------------------------
__global__ __launch_bounds__(256) void prep(
    const float* __restrict__ W1a, const float* __restrict__ W1b,
    const float* __restrict__ Wf, const float* __restrict__ W2,
    u16* __restrict__ W1at, u16* __restrict__ W1bt, u16* __restrict__ Wft,
    u16* __restrict__ W2t, const int* __restrict__ rows,
    int* __restrict__ cnt) {
  __shared__ int hsh[NBUCK];
  const int b = blockIdx.x;
  const int tid = threadIdx.x;
  if (b < WT_BLKS) {
    const int i = b * 256 + tid;
    if (i < 65536) {
      const int n = i >> 8, k = i & 255;
      W1at[i] = f2bf(W1a[k * 256 + n]);
    } else if (i < 98304) {
      const int t = i - 65536;
      const int n = t >> 7, k = t & 127;
      W1bt[t] = f2bf(W1b[k * 256 + n]);
    } else if (i < 163840) {
      const int t = i - 98304;
      const int n = t >> 8, k = t & 255;
      Wft[t] = f2bf(Wf[k * 256 + n]);
    } else if (i < 180224) {
      const int t = i - 163840;
      const int n = t >> 8, p = t & 255;
      const int f = ((p >> 6) << 6) + ((p & 3) << 4) + ((p >> 2) & 15);
      W2t[t] = f2bf(W2[f * 64 + n]);
    }
  } else {
    const int blk = b - WT_BLKS;
    for (int i = tid; i < NBUCK; i += 256) hsh[i] = 0;
    __syncthreads();
    const int s = blk * CHUNK;
    const int e = s + CHUNK;
    for (int i = s + tid; i < e; i += 256) atomicAdd(&hsh[rows[i] >> 6], 1);
    __syncthreads();
    for (int i = tid; i < NBUCK; i += 256) cnt[i * PBLK + blk] = hsh[i];
  }
}

// ---------------------------------------------------------------------------
// L2 (512 thr): gemm1 (fp32 A) | gemm2 (fp32 A) | s1 per-bucket scan
// ---------------------------------------------------------------------------
__global__ __launch_bounds__(512) void gemm12_s1(
    const float* __restrict__ xa, const u16* __restrict__ W1at,
    const float* __restrict__ b1a, const float* __restrict__ xb,
    const u16* __restrict__ W1bt, const float* __restrict__ b1b,
    u16* __restrict__ h, int* __restrict__ cnt, int* __restrict__ btot) {
  __shared__ __align__(16) u16 As[128 * 64];
  __shared__ __align__(16) u16 Bs[256 * 64];
  const int b = blockIdx.x;
  if (b < G1_BLKS) {
    gemm8_af32(b, xa, W1at, b1a, h, NA, 256, As, Bs);
  } else if (b < G1_BLKS + G2_BLKS) {
    gemm8_af32(b - G1_BLKS, xb, W1bt, b1b, h + (size_t)NA * NHID, NB, 128, As,
               Bs);
  } else {
    int* lds = (int*)As;
    const int bu = b - (G1_BLKS + G2_BLKS);
    const int t = threadIdx.x;
    const int v = (t < PBLK) ? cnt[bu * PBLK + t] : 0;
    lds[t] = v;
    __syncthreads();
#pragma unroll
    for (int off = 1; off < PBLK; off <<= 1) {
      const int x = (t >= off) ? lds[t - off] : 0;
      __syncthreads();
      lds[t] += x;
      __syncthreads();
    }
    if (t < PBLK) cnt[bu * PBLK + t] = lds[t] - v;
    if (t == PBLK - 1) btot[bu] = lds[t];
  }
}

// ---------------------------------------------------------------------------
// L3a (512 thr): gemm3 first half | s2 scan (global bstart) | p3 scatter
// ---------------------------------------------------------------------------
__global__ __launch_bounds__(512) void gemm3a_s2_p3(
    const u16* __restrict__ h, const u16* __restrict__ Wft,
    const float* __restrict__ bfv, u32* __restrict__ zq,
    float* __restrict__ zscale, const int* __restrict__ btot,
    int* __restrict__ bstart, const int* __restrict__ rows,
    const int* __restrict__ cols, const float* __restrict__ vals,
    const int* __restrict__ cnt, int2* __restrict__ edges) {
  __shared__ __align__(16) u16 As[128 * 64];
  __shared__ __align__(16) u16 Bs[256 * 64];
  const int b = blockIdx.x;
  const int t = threadIdx.x;
  if (b < G3A) {
    gemm8_body<1>(b, h, Wft, bfv, zq, zscale, NN, 256, As, Bs);
  } else if (b == G3A) {
    int* lds = (int*)As;
    int carry = 0;
    for (int base = 0; base < NBUCK; base += 512) {
      const int i = base + t;
      const int v = (i < NBUCK) ? btot[i] : 0;
      lds[t] = v;
      __syncthreads();
#pragma unroll
      for (int off = 1; off < 512; off <<= 1) {
        const int x = (t >= off) ? lds[t - off] : 0;
        __syncthreads();
        lds[t] += x;
        __syncthreads();
      }
      const int excl = lds[t] - v;
      const int tot = lds[511];
      if (i < NBUCK) bstart[i] = carry + excl;
      __syncthreads();
      carry += tot;
    }
    if (t == 0) bstart[NBUCK] = NE;
  } else {
    // p3: local bstart scan (independent of s2), then scatter chunk
    const int blk = b - (G3A + 1);
    int* lbs = (int*)As;
    int* tmp = (int*)Bs;
    int carry = 0;
    for (int base = 0; base < NBUCK; base += 512) {
      const int i = base + t;
      const int v = (i < NBUCK) ? btot[i] : 0;
      tmp[t] = v;
      __syncthreads();
#pragma unroll
      for (int off = 1; off < 512; off <<= 1) {
        const int x = (t >= off) ? tmp[t - off] : 0;
        __syncthreads();
        tmp[t] += x;
        __syncthreads();
      }
      if (i < NBUCK) lbs[i] = carry + tmp[t] - v;
      const int tot = tmp[511];
      __syncthreads();
      carry += tot;
    }
    for (int bu = t; bu < NBUCK; bu += 512) lbs[bu] += cnt[bu * PBLK + blk];
    __syncthreads();
    const int s = blk * CHUNK;
    const int e = s + CHUNK;
    for (int i = s + t; i < e; i += 512) {
      const int r = rows[i];
      const int pos = atomicAdd(&lbs[r >> 6], 1);
      edges[pos] =
          make_int2(cols[i] | ((r & 63) << 17), __float_as_int(vals[i]));
    }
  }
}

// ---------------------------------------------------------------------------
// L3b (512 thr): gemm3 second half | per-bucket sort -> 4B records + rptr
// ---------------------------------------------------------------------------
__global__ __launch_bounds__(512) void gemm3b_sort(
    const u16* __restrict__ h, const u16* __restrict__ Wft,
    const float* __restrict__ bfv, u32* __restrict__ zq,
    float* __restrict__ zscale, const int* __restrict__ bstart,
    const int2* __restrict__ edges, u32* __restrict__ edges2,
    int* __restrict__ rptr) {
  __shared__ __align__(16) u16 As[128 * 64];
  __shared__ __align__(16) u16 Bs[256 * 64];
  __shared__ int hist[RPB];
  __shared__ int sc[RPB];
  __shared__ int cur[RPB];
  const int b = blockIdx.x;
  const int t = threadIdx.x;
  if (b < G3B) {
    gemm8_body<1>(b + G3A, h, Wft, bfv, zq, zscale, NN, 256, As, Bs);
  } else {
    const int bu = b - G3B;
    const int s = bstart[bu], e = bstart[bu + 1];
    if (t < RPB) hist[t] = 0;
    __syncthreads();
    for (int i = s + t; i < e; i += 512)
      atomicAdd(&hist[(edges[i].x >> 17) & 63], 1);
    __syncthreads();
    const int hv = (t < RPB) ? hist[t] : 0;
    if (t < RPB) sc[t] = hv;
    __syncthreads();
#pragma unroll
    for (int off = 1; off < RPB; off <<= 1) {
      const int x = (t >= off && t < RPB) ? sc[t - off] : 0;
      __syncthreads();
      if (t < RPB) sc[t] += x;
      __syncthreads();
    }
    if (t < RPB) {
      const int base = s + sc[t] - hv;
      cur[t] = base;
      const int grow = bu * RPB + t;
      if (grow < NN) rptr[grow] = base;
    }
    if (bu == 0 && t == 0) rptr[NN] = NE;
    __syncthreads();
    for (int i = s + t; i < e; i += 512) {
      const int2 ed = edges[i];
      const int lr = (ed.x >> 17) & 63;
      const int pos = atomicAdd(&cur[lr], 1);
      edges2[pos] = (u32)(ed.x & 0x1FFFF) |
                    ((u32)f2h(__int_as_float(ed.y)) << 17);
    }
  }
}

// ---------------------------------------------------------------------------
// L4: CSR SpMM width 256, biased-uint8 payload, 4B edges, relu+bf16 out.
// ---------------------------------------------------------------------------
__global__ __launch_bounds__(256) void spmm256_q8(
    const int* __restrict__ ptr, const u32* __restrict__ edges,
    const u32* __restrict__ Zq, const float* __restrict__ scales,
    u16* __restrict__ Yb) {
  const int wid = (int)((blockIdx.x * (size_t)256 + threadIdx.x) >> 6);
  const int lane = threadIdx.x & 63;
  if (wid >= NN) return;
  const int s = ptr[wid], e = ptr[wid + 1];
  const int gsel = lane >> 4;
  float a0 = 0.f, a1 = 0.f, a2 = 0.f, a3 = 0.f, S = 0.f;
  int j = s;
  for (; j + 7 < e; j += 8) {
    u32 ed[8];
#pragma unroll
    for (int q = 0; q < 8; ++q) ed[q] = edges[j + q];
    u32 dw[8];
    float sc[8];
#pragma unroll
    for (int q = 0; q < 8; ++q) {
      const int c = ed[q] & 0x1FFFF;
      dw[q] = Zq[(size_t)c * 64 + lane];
      sc[q] = scales[(size_t)c * 4 + gsel];
    }
#pragma unroll
    for (int q = 0; q < 8; ++q) {
      const float vs = h2f(ed[q] >> 17) * sc[q];
      S += vs;
      a0 += vs * (float)(dw[q] & 0xffu);
      a1 += vs * (float)((dw[q] >> 8) & 0xffu);
      a2 += vs * (float)((dw[q] >> 16) & 0xffu);
      a3 += vs * (float)(dw[q] >> 24);
    }
  }
  for (; j < e; ++j) {
    const u32 ed = edges[j];
    const int c = ed & 0x1FFFF;
    const u32 dw = Zq[(size_t)c * 64 + lane];
    const float vs = h2f(ed >> 17) * scales[(size_t)c * 4 + gsel];
    S += vs;
    a0 += vs * (float)(dw & 0xffu);
    a1 += vs * (float)((dw >> 8) & 0xffu);
    a2 += vs * (float)((dw >> 16) & 0xffu);
    a3 += vs * (float)(dw >> 24);
  }
  const float corr = 128.f * S;
  ushort4 o;
  o.x = f2bf(fmaxf(a0 - corr, 0.f));
  o.y = f2bf(fmaxf(a1 - corr, 0.f));
  o.z = f2bf(fmaxf(a2 - corr, 0.f));
  o.w = f2bf(fmaxf(a3 - corr, 0.f));
  reinterpret_cast<ushort4*>(Yb + (size_t)wid * 256)[lane] = o;
}

// ---------------------------------------------------------------------------
// L6: CSR SpMM width 64, biased-uint8 payload, 4B edges, fp32 out.
// ---------------------------------------------------------------------------
__global__ __launch_bounds__(256) void spmm64_q8(
    const int* __restrict__ ptr, const u32* __restrict__ edges,
    const u32* __restrict__ Z2q, const float* __restrict__ zsc2,
    float* __restrict__ Y) {
  const int wid = (int)((blockIdx.x * (size_t)256 + threadIdx.x) >> 6);
  const int lane = threadIdx.x & 63;
  if (wid >= NN) return;
  const int s = ptr[wid], e = ptr[wid + 1];
  const int dwi = lane & 15;
  const int bsh = (lane >> 4) * 8;
  float acc = 0.f, S = 0.f;
  int j = s;
  for (; j + 7 < e; j += 8) {
    u32 ed[8];
#pragma unroll
    for (int q = 0; q < 8; ++q) ed[q] = edges[j + q];
    u32 dw[8];
    float sc[8];
#pragma unroll
    for (int q = 0; q < 8; ++q) {
      const int c = ed[q] & 0x1FFFF;
      dw[q] = Z2q[(size_t)c * 16 + dwi];
      sc[q] = zsc2[c];
    }
#pragma unroll
    for (int q = 0; q < 8; ++q) {
      const float vs = h2f(ed[q] >> 17) * sc[q];
      S += vs;
      acc += vs * (float)((dw[q] >> bsh) & 0xffu);
    }
  }
  for (; j < e; ++j) {
    const u32 ed = edges[j];
    const int c = ed & 0x1FFFF;
    const float vs = h2f(ed >> 17) * zsc2[c];
    S += vs;
    acc += vs * (float)((Z2q[(size_t)c * 16 + dwi] >> bsh) & 0xffu);
  }
  Y[(size_t)wid * 64 + lane] = acc - 128.f * S;
}

extern "C" void kernel_launch(void* const* d_in, const int* in_sizes, int n_in,
                              void* d_out, int out_size, void* d_ws,
                              size_t ws_size, hipStream_t stream) {
  const float* x_a  = (const float*)d_in[0];
  const float* x_b  = (const float*)d_in[1];
  const int*   rows = (const int*)d_in[2];
  const int*   cols = (const int*)d_in[3];
  const float* vals = (const float*)d_in[4];
  const float* W1a  = (const float*)d_in[5];
  const float* b1a  = (const float*)d_in[6];
  const float* W1b  = (const float*)d_in[7];
  const float* b1b  = (const float*)d_in[8];
  const float* Wf   = (const float*)d_in[9];
  const float* bf   = (const float*)d_in[10];
  const float* W2   = (const float*)d_in[11];
  const float* b2   = (const float*)d_in[12];
  float* out = (float*)d_out;

  // workspace (~130 MB)
  char* p = (char*)d_ws;
  u16* h    = (u16*)p;  p += (size_t)NN * NHID * 2;   // 51.2MB (h, later s1b)
  u32* zq   = (u32*)p;  p += (size_t)NN * 64 * 4;     // 25.6MB uint8 z
  float* zscale = (float*)p; p += (size_t)NN * 4 * 4; // 1.6MB
  u32* z2q  = (u32*)p;  p += (size_t)NN * 16 * 4;     // 6.4MB uint8 z2
  float* zsc2 = (float*)p; p += (size_t)NN * 4;       // 0.4MB
  u32* edges2 = (u32*)p;  p += (size_t)NE * 4;        // 12.8MB (4B records)
  u16* W1at = (u16*)p;  p += 256 * 256 * 2;
  u16* W1bt = (u16*)p;  p += 256 * 128 * 2;
  u16* Wft  = (u16*)p;  p += 256 * 256 * 2;
  u16* W2t  = (u16*)p;  p += 64 * 256 * 2;
  int2* edges = (int2*)p; p += (size_t)NE * 8;        // 25.6MB
  int* cnt    = (int*)p;  p += (size_t)NBUCK * PBLK * 4;
  int* btot   = (int*)p;  p += (size_t)((NBUCK + 3) & ~3) * 4;
  int* bstart = (int*)p;  p += (size_t)((NBUCK + 4) & ~3) * 4;
  int* rptr   = (int*)p;  p += (size_t)(NN + 4) * 4;
  u16* s1b = h;

  // L1: weight transposes | p1 histogram
  prep<<<WT_BLKS + PBLK, 256, 0, stream>>>(W1a, W1b, Wf, W2, W1at, W1bt, Wft,
                                           W2t, rows, cnt);

  // L2: gemm1 | gemm2 (fp32 A, BK=64) | s1 scan
  gemm12_s1<<<G1_BLKS + G2_BLKS + NBUCK, 512, 0, stream>>>(
      x_a, W1at, b1a, x_b, W1bt, b1b, h, cnt, btot);

  // L3a: gemm3 first half (BK=64) | s2 | p3 scatter
  gemm3a_s2_p3<<<G3A + 1 + PBLK, 512, 0, stream>>>(
      h, Wft, bf, zq, zscale, btot, bstart, rows, cols, vals, cnt, edges);

  // L3b: gemm3 second half (BK=64) | per-bucket row sort -> 4B records
  gemm3b_sort<<<G3B + NBUCK, 512, 0, stream>>>(h, Wft, bf, zq, zscale, bstart,
                                               edges, edges2, rptr);

  // L4: s1b = bf16(relu(spmm(zq)))  (permuted feature order)
  spmm256_q8<<<(NN * 64 + 255) / 256, 256, 0, stream>>>(rptr, edges2, zq,
                                                        zscale, s1b);
  // L5: z2q = uint8(s1b @ W2t^T + b2), per-row scale (BK=64)
  gemm4_q8<<<G3_BLKS, 256, 0, stream>>>(s1b, W2t, b2, z2q, zsc2, NN, 256);
  // L6: out = spmm(z2q)
  spmm64_q8<<<(NN * 64 + 255) / 256, 256, 0, stream>>>(rptr, edges2, z2q,
                                                       zsc2, out);
}